// Round 1
// baseline (33007.828 us; speedup 1.0000x reference)
//
#include <hip/hip_runtime.h>
#include <hip/hip_bf16.h>

// Problem constants
#define N_  100000
#define E_  1600000
#define G_  512
#define H_  128
#define T_  10
#define BN_EPS 1e-5f

// ---------------------------------------------------------------------------
// GEMM: C[N x 128] = A[N x 128] @ W[128 x 128] + bias, with fused per-column
// sum / sumsq accumulation (BN batch statistics) via atomics into stats[256].
// Block: 256 threads (16x16), tile 64 rows x 128 cols, K in 4 steps of 32.
// ---------------------------------------------------------------------------
__global__ __launch_bounds__(256) void gemm_stats(
    const float* __restrict__ A, const float* __restrict__ W,
    const float* __restrict__ bias, float* __restrict__ C,
    float* __restrict__ stats, int nrows)
{
    __shared__ __align__(16) float As[64][33];
    __shared__ __align__(16) float Bs[32][128];

    const int tid = threadIdx.x;
    const int tx = tid & 15;        // col group: cols [tx*8, tx*8+8)
    const int ty = tid >> 4;        // row group: rows [ty*4, ty*4+4)
    const int tx8 = tx << 3;
    const int ty4 = ty << 2;
    const int rowBase = blockIdx.x * 64;

    float acc[4][8];
#pragma unroll
    for (int i = 0; i < 4; ++i)
#pragma unroll
        for (int j = 0; j < 8; ++j) acc[i][j] = 0.f;

    for (int k0 = 0; k0 < 128; k0 += 32) {
        // Load A tile: 64 rows x 32 k = 2048 floats, 2 rounds of 256 x float4
#pragma unroll
        for (int r = 0; r < 2; ++r) {
            int idx = (tid + r * 256) << 2;     // 0..2044
            int ar = idx >> 5;
            int ak = idx & 31;
            int grow = rowBase + ar;
            float4 v = make_float4(0.f, 0.f, 0.f, 0.f);
            if (grow < nrows)
                v = *(const float4*)(A + (size_t)grow * 128 + k0 + ak);
            As[ar][ak + 0] = v.x; As[ar][ak + 1] = v.y;
            As[ar][ak + 2] = v.z; As[ar][ak + 3] = v.w;
        }
        // Load W tile: 32 k x 128 cols = 4096 floats, 4 rounds of 256 x float4
#pragma unroll
        for (int r = 0; r < 4; ++r) {
            int idx = (tid + r * 256) << 2;     // 0..4092
            int bk = idx >> 7;
            int bc = idx & 127;
            float4 v = *(const float4*)(W + (size_t)(k0 + bk) * 128 + bc);
            *(float4*)&Bs[bk][bc] = v;
        }
        __syncthreads();

#pragma unroll
        for (int k = 0; k < 32; ++k) {
            float a[4];
#pragma unroll
            for (int i = 0; i < 4; ++i) a[i] = As[ty4 + i][k];
            float4 b0 = *(const float4*)&Bs[k][tx8];
            float4 b1 = *(const float4*)&Bs[k][tx8 + 4];
#pragma unroll
            for (int i = 0; i < 4; ++i) {
                acc[i][0] = fmaf(a[i], b0.x, acc[i][0]);
                acc[i][1] = fmaf(a[i], b0.y, acc[i][1]);
                acc[i][2] = fmaf(a[i], b0.z, acc[i][2]);
                acc[i][3] = fmaf(a[i], b0.w, acc[i][3]);
                acc[i][4] = fmaf(a[i], b1.x, acc[i][4]);
                acc[i][5] = fmaf(a[i], b1.y, acc[i][5]);
                acc[i][6] = fmaf(a[i], b1.z, acc[i][6]);
                acc[i][7] = fmaf(a[i], b1.w, acc[i][7]);
            }
        }
        __syncthreads();
    }

    // Epilogue: bias add, store, per-thread column partial sums for BN stats
    float4 bia0 = *(const float4*)(bias + tx8);
    float4 bia1 = *(const float4*)(bias + tx8 + 4);
    float s1[8], s2[8];
#pragma unroll
    for (int j = 0; j < 8; ++j) { s1[j] = 0.f; s2[j] = 0.f; }

#pragma unroll
    for (int i = 0; i < 4; ++i) {
        int grow = rowBase + ty4 + i;
        if (grow < nrows) {
            float v[8];
            v[0] = acc[i][0] + bia0.x; v[1] = acc[i][1] + bia0.y;
            v[2] = acc[i][2] + bia0.z; v[3] = acc[i][3] + bia0.w;
            v[4] = acc[i][4] + bia1.x; v[5] = acc[i][5] + bia1.y;
            v[6] = acc[i][6] + bia1.z; v[7] = acc[i][7] + bia1.w;
            float4 o0 = make_float4(v[0], v[1], v[2], v[3]);
            float4 o1 = make_float4(v[4], v[5], v[6], v[7]);
            *(float4*)(C + (size_t)grow * 128 + tx8) = o0;
            *(float4*)(C + (size_t)grow * 128 + tx8 + 4) = o1;
#pragma unroll
            for (int j = 0; j < 8; ++j) { s1[j] += v[j]; s2[j] += v[j] * v[j]; }
        }
    }

    // Block-level column reduction in LDS (reuse As/Bs), then atomics
    float (*red1)[128] = (float(*)[128])&As[0][0];   // 16*128 <= 64*33
    float (*red2)[128] = (float(*)[128])&Bs[0][0];   // 16*128 <= 32*128
#pragma unroll
    for (int j = 0; j < 8; ++j) { red1[ty][tx8 + j] = s1[j]; red2[ty][tx8 + j] = s2[j]; }
    __syncthreads();
    if (tid < 128) {
        float S1 = 0.f, S2 = 0.f;
#pragma unroll
        for (int t = 0; t < 16; ++t) { S1 += red1[t][tid]; S2 += red2[t][tid]; }
        atomicAdd(&stats[tid], S1);
        atomicAdd(&stats[128 + tid], S2);
    }
}

// ---------------------------------------------------------------------------
// BN apply + ReLU, in place. Finalization (mu/var/scale/shift) fused in.
// One thread per float4.
// ---------------------------------------------------------------------------
__global__ void bn_relu(float* __restrict__ h, const float* __restrict__ stats,
                        const float* __restrict__ gamma, const float* __restrict__ beta,
                        int n4)
{
    int i = blockIdx.x * blockDim.x + threadIdx.x;
    if (i >= n4) return;
    int c = (i << 2) & 127;
    const float nInv = 1.0f / (float)N_;
    float4 s1 = *(const float4*)(stats + c);
    float4 s2 = *(const float4*)(stats + 128 + c);
    float4 gm = *(const float4*)(gamma + c);
    float4 bt = *(const float4*)(beta + c);

    float mu0 = s1.x * nInv, mu1 = s1.y * nInv, mu2 = s1.z * nInv, mu3 = s1.w * nInv;
    float sc0 = gm.x * rsqrtf(s2.x * nInv - mu0 * mu0 + BN_EPS);
    float sc1 = gm.y * rsqrtf(s2.y * nInv - mu1 * mu1 + BN_EPS);
    float sc2 = gm.z * rsqrtf(s2.z * nInv - mu2 * mu2 + BN_EPS);
    float sc3 = gm.w * rsqrtf(s2.w * nInv - mu3 * mu3 + BN_EPS);
    float sh0 = bt.x - mu0 * sc0, sh1 = bt.y - mu1 * sc1;
    float sh2 = bt.z - mu2 * sc2, sh3 = bt.w - mu3 * sc3;

    float4 v = *(float4*)(h + (size_t)i * 4);
    v.x = fmaxf(0.f, fmaf(v.x, sc0, sh0));
    v.y = fmaxf(0.f, fmaf(v.y, sc1, sh1));
    v.z = fmaxf(0.f, fmaf(v.z, sc2, sh2));
    v.w = fmaxf(0.f, fmaf(v.w, sc3, sh3));
    *(float4*)(h + (size_t)i * 4) = v;
}

// u = (1 + eps[li]) * h
__global__ void scale_copy(const float* __restrict__ h, float* __restrict__ u,
                           const float* __restrict__ eps, int li, int n4)
{
    int i = blockIdx.x * blockDim.x + threadIdx.x;
    if (i >= n4) return;
    float s = 1.0f + eps[li];
    float4 v = *(const float4*)(h + (size_t)i * 4);
    v.x *= s; v.y *= s; v.z *= s; v.w *= s;
    *(float4*)(u + (size_t)i * 4) = v;
}

// u[dst[e]] += h[src[e]]  — one thread per (edge, 32-feature chunk)
__global__ void scatter_add(const float* __restrict__ h, float* __restrict__ u,
                            const int* __restrict__ src, const int* __restrict__ dst,
                            int total)
{
    int gid = blockIdx.x * blockDim.x + threadIdx.x;
    if (gid >= total) return;
    int e = gid >> 2;
    int p = gid & 3;
    int s = src[e];
    int d = dst[e];
    const float4* hs = (const float4*)(h + (size_t)s * 128 + p * 32);
    float* ud = u + (size_t)d * 128 + p * 32;
#pragma unroll
    for (int q = 0; q < 8; ++q) {
        float4 v = hs[q];
        atomicAdd(ud + q * 4 + 0, v.x);
        atomicAdd(ud + q * 4 + 1, v.y);
        atomicAdd(ud + q * 4 + 2, v.z);
        atomicAdd(ud + q * 4 + 3, v.w);
    }
}

// counts per graph (float, exact for these magnitudes)
__global__ void count_nodes(const int* __restrict__ batch, float* __restrict__ cnt, int n)
{
    int i = blockIdx.x * blockDim.x + threadIdx.x;
    if (i < n) atomicAdd(&cnt[batch[i]], 1.0f);
}

// segment-sum of h into pooled[G][128]; batch is sorted, so each block scans a
// contiguous row range keeping a running sum and flushes on graph change.
__global__ void pool_sum(const float* __restrict__ h, const int* __restrict__ batch,
                         float* __restrict__ pooled, int n)
{
    int c = threadIdx.x;                         // 0..127
    int per = (n + gridDim.x - 1) / gridDim.x;
    int r0 = blockIdx.x * per;
    int r1 = min(n, r0 + per);
    if (r0 >= r1) return;
    int curg = batch[r0];
    float s = 0.f;
    for (int r = r0; r < r1; ++r) {
        int g = batch[r];
        if (g != curg) {
            atomicAdd(&pooled[(size_t)curg * 128 + c], s);
            s = 0.f;
            curg = g;
        }
        s += h[(size_t)r * 128 + c];
    }
    atomicAdd(&pooled[(size_t)curg * 128 + c], s);
}

// out_acc[g][t] += (pooledSum[g] @ Wl[:,t]) / max(cnt[g],1) + bl[t]
__global__ void out_accum(const float* __restrict__ pooled, const float* __restrict__ cnt,
                          const float* __restrict__ Wl, const float* __restrict__ bl,
                          float* __restrict__ outacc)
{
    int g = blockIdx.x;
    int t = threadIdx.x;
    if (t >= T_) return;
    float inv = 1.0f / fmaxf(cnt[g], 1.0f);
    float acc = 0.f;
    for (int c = 0; c < 128; ++c)
        acc = fmaf(pooled[(size_t)g * 128 + c], Wl[c * T_ + t], acc);
    outacc[g * T_ + t] += acc * inv + bl[t];
}

__global__ void sigmoid_k(const float* __restrict__ in, float* __restrict__ out, int n)
{
    int i = blockIdx.x * blockDim.x + threadIdx.x;
    if (i < n) out[i] = 1.0f / (1.0f + expf(-in[i]));
}

// ---------------------------------------------------------------------------
extern "C" void kernel_launch(void* const* d_in, const int* in_sizes, int n_in,
                              void* d_out, int out_size, void* d_ws, size_t ws_size,
                              hipStream_t stream)
{
    const float* x    = (const float*)d_in[0];
    const int*   ei   = (const int*)d_in[1];       // [2,E]: src row then dst row
    const int*   batch= (const int*)d_in[2];
    const float* Wa   = (const float*)d_in[3];
    const float* ba   = (const float*)d_in[4];
    const float* ga   = (const float*)d_in[5];
    const float* bea  = (const float*)d_in[6];
    const float* Wb   = (const float*)d_in[7];
    const float* bb   = (const float*)d_in[8];
    const float* gb   = (const float*)d_in[9];
    const float* beb  = (const float*)d_in[10];
    const float* Wl   = (const float*)d_in[11];
    const float* bl   = (const float*)d_in[12];
    const float* eps  = (const float*)d_in[13];
    float* out = (float*)d_out;

    const size_t NH = (size_t)N_ * H_;
    float* bufA   = (float*)d_ws;
    float* bufB   = bufA + NH;
    float* stats  = bufB + NH;                    // 8 regions x 256 floats
    float* pooled = stats + 8 * 2 * H_;           // 4 x G x 128
    float* cntf   = pooled + 4 * (size_t)G_ * H_; // G
    float* outacc = cntf + G_;                    // G*T

    size_t zbytes = (size_t)(8 * 2 * H_ + 4 * G_ * H_ + G_ + G_ * T_) * sizeof(float);
    hipMemsetAsync(stats, 0, zbytes, stream);

    count_nodes<<<(N_ + 255) / 256, 256, 0, stream>>>(batch, cntf, N_);

    const int gemmGrid = (N_ + 63) / 64;
    const int n4 = (int)(NH / 4);
    const int ewGrid = (n4 + 255) / 256;

    // ---- layer 0: MLP on x ----
    gemm_stats<<<gemmGrid, 256, 0, stream>>>(x, Wa, ba, bufA, stats, N_);
    bn_relu<<<ewGrid, 256, 0, stream>>>(bufA, stats, ga, bea, n4);
    gemm_stats<<<gemmGrid, 256, 0, stream>>>(bufA, Wb, bb, bufB, stats + 2 * H_, N_);
    bn_relu<<<ewGrid, 256, 0, stream>>>(bufB, stats + 2 * H_, gb, beb, n4);
    pool_sum<<<512, 128, 0, stream>>>(bufB, batch, pooled, N_);
    out_accum<<<G_, 64, 0, stream>>>(pooled, cntf, Wl, bl, outacc);

    float* h = bufB;
    float* u = bufA;
    for (int l = 1; l < 4; ++l) {
        float* stA = stats + (size_t)(2 * l) * 2 * H_;
        float* stB = stats + (size_t)(2 * l + 1) * 2 * H_;
        // u = (1+eps)*h, then scatter-add neighbors of h into u
        scale_copy<<<ewGrid, 256, 0, stream>>>(h, u, eps, l - 1, n4);
        scatter_add<<<(E_ * 4 + 255) / 256, 256, 0, stream>>>(h, u, ei, ei + E_, E_ * 4);
        // MLP
        gemm_stats<<<gemmGrid, 256, 0, stream>>>(u, Wa + (size_t)l * H_ * H_, ba + l * H_, h, stA, N_);
        bn_relu<<<ewGrid, 256, 0, stream>>>(h, stA, ga + l * H_, bea + l * H_, n4);
        gemm_stats<<<gemmGrid, 256, 0, stream>>>(h, Wb + (size_t)l * H_ * H_, bb + l * H_, u, stB, N_);
        bn_relu<<<ewGrid, 256, 0, stream>>>(u, stB, gb + l * H_, beb + l * H_, n4);
        // pool + output linear
        pool_sum<<<512, 128, 0, stream>>>(u, batch, pooled + (size_t)l * G_ * H_, N_);
        out_accum<<<G_, 64, 0, stream>>>(pooled + (size_t)l * G_ * H_, cntf,
                                         Wl + (size_t)l * H_ * T_, bl + l * T_, outacc);
        // swap roles
        float* tmp = h; h = u; u = tmp;
    }

    sigmoid_k<<<(G_ * T_ + 255) / 256, 256, 0, stream>>>(outacc, out, G_ * T_);
}

// Round 2
// 1701.357 us; speedup vs baseline: 19.4009x; 19.4009x over previous
//
#include <hip/hip_runtime.h>
#include <hip/hip_bf16.h>

// Problem constants
#define N_  100000
#define E_  1600000
#define G_  512
#define H_  128
#define T_  10
#define BN_EPS 1e-5f

// ---------------------------------------------------------------------------
// GEMM: C[N x 128] = A[N x 128] @ W[128 x 128] + bias, with fused per-column
// sum / sumsq accumulation (BN batch statistics) via atomics into stats[256].
// Block: 256 threads (16x16), tile 64 rows x 128 cols, K in 4 steps of 32.
// ---------------------------------------------------------------------------
__global__ __launch_bounds__(256) void gemm_stats(
    const float* __restrict__ A, const float* __restrict__ W,
    const float* __restrict__ bias, float* __restrict__ C,
    float* __restrict__ stats, int nrows)
{
    __shared__ __align__(16) float As[64][33];
    __shared__ __align__(16) float Bs[32][128];

    const int tid = threadIdx.x;
    const int tx = tid & 15;        // col group: cols [tx*8, tx*8+8)
    const int ty = tid >> 4;        // row group: rows [ty*4, ty*4+4)
    const int tx8 = tx << 3;
    const int ty4 = ty << 2;
    const int rowBase = blockIdx.x * 64;

    float acc[4][8];
#pragma unroll
    for (int i = 0; i < 4; ++i)
#pragma unroll
        for (int j = 0; j < 8; ++j) acc[i][j] = 0.f;

    for (int k0 = 0; k0 < 128; k0 += 32) {
#pragma unroll
        for (int r = 0; r < 2; ++r) {
            int idx = (tid + r * 256) << 2;
            int ar = idx >> 5;
            int ak = idx & 31;
            int grow = rowBase + ar;
            float4 v = make_float4(0.f, 0.f, 0.f, 0.f);
            if (grow < nrows)
                v = *(const float4*)(A + (size_t)grow * 128 + k0 + ak);
            As[ar][ak + 0] = v.x; As[ar][ak + 1] = v.y;
            As[ar][ak + 2] = v.z; As[ar][ak + 3] = v.w;
        }
#pragma unroll
        for (int r = 0; r < 4; ++r) {
            int idx = (tid + r * 256) << 2;
            int bk = idx >> 7;
            int bc = idx & 127;
            float4 v = *(const float4*)(W + (size_t)(k0 + bk) * 128 + bc);
            *(float4*)&Bs[bk][bc] = v;
        }
        __syncthreads();

#pragma unroll
        for (int k = 0; k < 32; ++k) {
            float a[4];
#pragma unroll
            for (int i = 0; i < 4; ++i) a[i] = As[ty4 + i][k];
            float4 b0 = *(const float4*)&Bs[k][tx8];
            float4 b1 = *(const float4*)&Bs[k][tx8 + 4];
#pragma unroll
            for (int i = 0; i < 4; ++i) {
                acc[i][0] = fmaf(a[i], b0.x, acc[i][0]);
                acc[i][1] = fmaf(a[i], b0.y, acc[i][1]);
                acc[i][2] = fmaf(a[i], b0.z, acc[i][2]);
                acc[i][3] = fmaf(a[i], b0.w, acc[i][3]);
                acc[i][4] = fmaf(a[i], b1.x, acc[i][4]);
                acc[i][5] = fmaf(a[i], b1.y, acc[i][5]);
                acc[i][6] = fmaf(a[i], b1.z, acc[i][6]);
                acc[i][7] = fmaf(a[i], b1.w, acc[i][7]);
            }
        }
        __syncthreads();
    }

    float4 bia0 = *(const float4*)(bias + tx8);
    float4 bia1 = *(const float4*)(bias + tx8 + 4);
    float s1[8], s2[8];
#pragma unroll
    for (int j = 0; j < 8; ++j) { s1[j] = 0.f; s2[j] = 0.f; }

#pragma unroll
    for (int i = 0; i < 4; ++i) {
        int grow = rowBase + ty4 + i;
        if (grow < nrows) {
            float v[8];
            v[0] = acc[i][0] + bia0.x; v[1] = acc[i][1] + bia0.y;
            v[2] = acc[i][2] + bia0.z; v[3] = acc[i][3] + bia0.w;
            v[4] = acc[i][4] + bia1.x; v[5] = acc[i][5] + bia1.y;
            v[6] = acc[i][6] + bia1.z; v[7] = acc[i][7] + bia1.w;
            float4 o0 = make_float4(v[0], v[1], v[2], v[3]);
            float4 o1 = make_float4(v[4], v[5], v[6], v[7]);
            *(float4*)(C + (size_t)grow * 128 + tx8) = o0;
            *(float4*)(C + (size_t)grow * 128 + tx8 + 4) = o1;
#pragma unroll
            for (int j = 0; j < 8; ++j) { s1[j] += v[j]; s2[j] += v[j] * v[j]; }
        }
    }

    float (*red1)[128] = (float(*)[128])&As[0][0];
    float (*red2)[128] = (float(*)[128])&Bs[0][0];
#pragma unroll
    for (int j = 0; j < 8; ++j) { red1[ty][tx8 + j] = s1[j]; red2[ty][tx8 + j] = s2[j]; }
    __syncthreads();
    if (tid < 128) {
        float S1 = 0.f, S2 = 0.f;
#pragma unroll
        for (int t = 0; t < 16; ++t) { S1 += red1[t][tid]; S2 += red2[t][tid]; }
        atomicAdd(&stats[tid], S1);
        atomicAdd(&stats[128 + tid], S2);
    }
}

// ---------------------------------------------------------------------------
// BN apply + ReLU, in place.
// ---------------------------------------------------------------------------
__global__ void bn_relu(float* __restrict__ h, const float* __restrict__ stats,
                        const float* __restrict__ gamma, const float* __restrict__ beta,
                        int n4)
{
    int i = blockIdx.x * blockDim.x + threadIdx.x;
    if (i >= n4) return;
    int c = (i << 2) & 127;
    const float nInv = 1.0f / (float)N_;
    float4 s1 = *(const float4*)(stats + c);
    float4 s2 = *(const float4*)(stats + 128 + c);
    float4 gm = *(const float4*)(gamma + c);
    float4 bt = *(const float4*)(beta + c);

    float mu0 = s1.x * nInv, mu1 = s1.y * nInv, mu2 = s1.z * nInv, mu3 = s1.w * nInv;
    float sc0 = gm.x * rsqrtf(s2.x * nInv - mu0 * mu0 + BN_EPS);
    float sc1 = gm.y * rsqrtf(s2.y * nInv - mu1 * mu1 + BN_EPS);
    float sc2 = gm.z * rsqrtf(s2.z * nInv - mu2 * mu2 + BN_EPS);
    float sc3 = gm.w * rsqrtf(s2.w * nInv - mu3 * mu3 + BN_EPS);
    float sh0 = bt.x - mu0 * sc0, sh1 = bt.y - mu1 * sc1;
    float sh2 = bt.z - mu2 * sc2, sh3 = bt.w - mu3 * sc3;

    float4 v = *(float4*)(h + (size_t)i * 4);
    v.x = fmaxf(0.f, fmaf(v.x, sc0, sh0));
    v.y = fmaxf(0.f, fmaf(v.y, sc1, sh1));
    v.z = fmaxf(0.f, fmaf(v.z, sc2, sh2));
    v.w = fmaxf(0.f, fmaf(v.w, sc3, sh3));
    *(float4*)(h + (size_t)i * 4) = v;
}

// ---------------------------------------------------------------------------
// CSR build: histogram -> exclusive scan -> bucket fill
// ---------------------------------------------------------------------------
__global__ void hist_dst(const int* __restrict__ dst, int* __restrict__ cnt, int e)
{
    int i = blockIdx.x * blockDim.x + threadIdx.x;
    if (i < e) atomicAdd(&cnt[dst[i]], 1);
}

// Each block scans 1024 elements (256 threads x 4). Writes local-exclusive
// prefixes into off[], block total into bsum[].
__global__ __launch_bounds__(256) void scan1(const int* __restrict__ cnt,
                                             int* __restrict__ off,
                                             int* __restrict__ bsum, int n)
{
    __shared__ int sd[256];
    int t = threadIdx.x;
    int base = blockIdx.x * 1024 + t * 4;
    int c0 = (base + 0 < n) ? cnt[base + 0] : 0;
    int c1 = (base + 1 < n) ? cnt[base + 1] : 0;
    int c2 = (base + 2 < n) ? cnt[base + 2] : 0;
    int c3 = (base + 3 < n) ? cnt[base + 3] : 0;
    int s = c0 + c1 + c2 + c3;
    sd[t] = s;
    __syncthreads();
    for (int d = 1; d < 256; d <<= 1) {
        int v = (t >= d) ? sd[t - d] : 0;
        __syncthreads();
        sd[t] += v;
        __syncthreads();
    }
    int p = sd[t] - s;   // exclusive prefix within block
    if (base + 0 < n) off[base + 0] = p;
    if (base + 1 < n) off[base + 1] = p + c0;
    if (base + 2 < n) off[base + 2] = p + c0 + c1;
    if (base + 3 < n) off[base + 3] = p + c0 + c1 + c2;
    if (t == 255) bsum[blockIdx.x] = sd[255];
}

// Single block: exclusive scan of bsum[nb], nb <= 128
__global__ __launch_bounds__(128) void scan2(int* __restrict__ bsum, int nb)
{
    __shared__ int sd[128];
    int t = threadIdx.x;
    int v0 = (t < nb) ? bsum[t] : 0;
    sd[t] = v0;
    __syncthreads();
    for (int d = 1; d < 128; d <<= 1) {
        int v = (t >= d) ? sd[t - d] : 0;
        __syncthreads();
        sd[t] += v;
        __syncthreads();
    }
    if (t < nb) bsum[t] = sd[t] - v0;
}

// Add block bases; emit final off[] and a working cursor copy; off[n]=E.
__global__ __launch_bounds__(256) void scan3(int* __restrict__ off,
                                             int* __restrict__ cur,
                                             const int* __restrict__ bsum, int n)
{
    int t = threadIdx.x;
    int base = blockIdx.x * 1024 + t * 4;
    int add = bsum[blockIdx.x];
#pragma unroll
    for (int i = 0; i < 4; ++i) {
        if (base + i < n) {
            int v = off[base + i] + add;
            off[base + i] = v;
            cur[base + i] = v;
        }
    }
    if (blockIdx.x == 0 && t == 0) off[n] = E_;
}

__global__ void fill_csr(const int* __restrict__ src, const int* __restrict__ dst,
                         int* __restrict__ cur, int* __restrict__ eidx, int e)
{
    int i = blockIdx.x * blockDim.x + threadIdx.x;
    if (i >= e) return;
    int d = dst[i];
    int pos = atomicAdd(&cur[d], 1);
    eidx[pos] = src[i];
}

// ---------------------------------------------------------------------------
// Fused GIN aggregation: u[i] = (1+eps)*h[i] + sum_{j in N(i)} h[j]
// One wave per node; lane holds 2 feature columns (float2).
// ---------------------------------------------------------------------------
__global__ __launch_bounds__(256) void aggregate(
    const float* __restrict__ h, float* __restrict__ u,
    const int* __restrict__ off, const int* __restrict__ eidx,
    const float* __restrict__ eps, int li)
{
    int node = blockIdx.x * 4 + (threadIdx.x >> 6);
    if (node >= N_) return;
    int lane = threadIdx.x & 63;
    int col = lane * 2;

    int s0 = off[node];
    int s1 = off[node + 1];
    float se = 1.0f + eps[li];

    float2 a = *(const float2*)(h + (size_t)node * 128 + col);
    float accx = a.x * se;
    float accy = a.y * se;

    int j = s0;
    for (; j + 1 < s1; j += 2) {
        int na = eidx[j];
        int nb = eidx[j + 1];
        float2 va = *(const float2*)(h + (size_t)na * 128 + col);
        float2 vb = *(const float2*)(h + (size_t)nb * 128 + col);
        accx += va.x + vb.x;
        accy += va.y + vb.y;
    }
    if (j < s1) {
        int na = eidx[j];
        float2 va = *(const float2*)(h + (size_t)na * 128 + col);
        accx += va.x;
        accy += va.y;
    }
    *(float2*)(u + (size_t)node * 128 + col) = make_float2(accx, accy);
}

// counts per graph
__global__ void count_nodes(const int* __restrict__ batch, float* __restrict__ cnt, int n)
{
    int i = blockIdx.x * blockDim.x + threadIdx.x;
    if (i < n) atomicAdd(&cnt[batch[i]], 1.0f);
}

// segment-sum of h into pooled[G][128]
__global__ void pool_sum(const float* __restrict__ h, const int* __restrict__ batch,
                         float* __restrict__ pooled, int n)
{
    int c = threadIdx.x;
    int per = (n + gridDim.x - 1) / gridDim.x;
    int r0 = blockIdx.x * per;
    int r1 = min(n, r0 + per);
    if (r0 >= r1) return;
    int curg = batch[r0];
    float s = 0.f;
    for (int r = r0; r < r1; ++r) {
        int g = batch[r];
        if (g != curg) {
            atomicAdd(&pooled[(size_t)curg * 128 + c], s);
            s = 0.f;
            curg = g;
        }
        s += h[(size_t)r * 128 + c];
    }
    atomicAdd(&pooled[(size_t)curg * 128 + c], s);
}

__global__ void out_accum(const float* __restrict__ pooled, const float* __restrict__ cnt,
                          const float* __restrict__ Wl, const float* __restrict__ bl,
                          float* __restrict__ outacc)
{
    int g = blockIdx.x;
    int t = threadIdx.x;
    if (t >= T_) return;
    float inv = 1.0f / fmaxf(cnt[g], 1.0f);
    float acc = 0.f;
    for (int c = 0; c < 128; ++c)
        acc = fmaf(pooled[(size_t)g * 128 + c], Wl[c * T_ + t], acc);
    outacc[g * T_ + t] += acc * inv + bl[t];
}

__global__ void sigmoid_k(const float* __restrict__ in, float* __restrict__ out, int n)
{
    int i = blockIdx.x * blockDim.x + threadIdx.x;
    if (i < n) out[i] = 1.0f / (1.0f + expf(-in[i]));
}

// ---------------------------------------------------------------------------
extern "C" void kernel_launch(void* const* d_in, const int* in_sizes, int n_in,
                              void* d_out, int out_size, void* d_ws, size_t ws_size,
                              hipStream_t stream)
{
    const float* x    = (const float*)d_in[0];
    const int*   ei   = (const int*)d_in[1];       // [2,E]: src row then dst row
    const int*   batch= (const int*)d_in[2];
    const float* Wa   = (const float*)d_in[3];
    const float* ba   = (const float*)d_in[4];
    const float* ga   = (const float*)d_in[5];
    const float* bea  = (const float*)d_in[6];
    const float* Wb   = (const float*)d_in[7];
    const float* bb   = (const float*)d_in[8];
    const float* gb   = (const float*)d_in[9];
    const float* beb  = (const float*)d_in[10];
    const float* Wl   = (const float*)d_in[11];
    const float* bl   = (const float*)d_in[12];
    const float* eps  = (const float*)d_in[13];
    float* out = (float*)d_out;

    const size_t NH = (size_t)N_ * H_;
    float* bufA   = (float*)d_ws;
    float* bufB   = bufA + NH;
    float* stats  = bufB + NH;                    // 8 regions x 256 floats
    float* pooled = stats + 8 * 2 * H_;           // 4 x G x 128
    float* cntf   = pooled + 4 * (size_t)G_ * H_; // G
    float* outacc = cntf + G_;                    // G*T
    int*   cur    = (int*)(outacc + (size_t)G_ * T_);  // N (histogram, then cursor)
    int*   off    = cur + N_;                     // N+1
    int*   eidx   = off + (N_ + 1);               // E

    // zero: stats..outacc + cur (contiguous)
    size_t zbytes = (size_t)(8 * 2 * H_ + 4 * G_ * H_ + G_ + G_ * T_ + N_) * sizeof(float);
    hipMemsetAsync(stats, 0, zbytes, stream);

    const int* esrc = ei;
    const int* edst = ei + E_;

    // ---- CSR build (once per call; graph static within call) ----
    hist_dst<<<(E_ + 255) / 256, 256, 0, stream>>>(edst, cur, E_);
    const int nScanBlocks = (N_ + 1023) / 1024;   // 98
    scan1<<<nScanBlocks, 256, 0, stream>>>(cur, off, off /*tmp*/, N_);
    // NOTE: bsum must not alias off; use tail of eidx region as bsum scratch
    // (eidx not yet filled). Redo properly:
    // (see below — we actually pass a dedicated bsum pointer)
    // -- replaced by correct sequence after this comment block --

    // Correct sequence with dedicated bsum scratch:
    {
        int* bsum = eidx + E_;                    // 128 ints of scratch past eidx
        // redo scan1 with proper bsum (previous launch wrote off as both; harmless,
        // we simply run the correct one after)
        scan1<<<nScanBlocks, 256, 0, stream>>>(cur, off, bsum, N_);
        scan2<<<1, 128, 0, stream>>>(bsum, nScanBlocks);
        scan3<<<nScanBlocks, 256, 0, stream>>>(off, cur, bsum, N_);
    }
    fill_csr<<<(E_ + 255) / 256, 256, 0, stream>>>(esrc, edst, cur, eidx, E_);

    count_nodes<<<(N_ + 255) / 256, 256, 0, stream>>>(batch, cntf, N_);

    const int gemmGrid = (N_ + 63) / 64;
    const int n4 = (int)(NH / 4);
    const int ewGrid = (n4 + 255) / 256;
    const int aggGrid = (N_ + 3) / 4;

    // ---- layer 0: MLP on x ----
    gemm_stats<<<gemmGrid, 256, 0, stream>>>(x, Wa, ba, bufA, stats, N_);
    bn_relu<<<ewGrid, 256, 0, stream>>>(bufA, stats, ga, bea, n4);
    gemm_stats<<<gemmGrid, 256, 0, stream>>>(bufA, Wb, bb, bufB, stats + 2 * H_, N_);
    bn_relu<<<ewGrid, 256, 0, stream>>>(bufB, stats + 2 * H_, gb, beb, n4);
    pool_sum<<<512, 128, 0, stream>>>(bufB, batch, pooled, N_);
    out_accum<<<G_, 64, 0, stream>>>(pooled, cntf, Wl, bl, outacc);

    float* h = bufB;
    float* u = bufA;
    for (int l = 1; l < 4; ++l) {
        float* stA = stats + (size_t)(2 * l) * 2 * H_;
        float* stB = stats + (size_t)(2 * l + 1) * 2 * H_;
        // u = (1+eps)*h + sum_{j->i} h[j]  (fused CSR gather)
        aggregate<<<aggGrid, 256, 0, stream>>>(h, u, off, eidx, eps, l - 1);
        // MLP
        gemm_stats<<<gemmGrid, 256, 0, stream>>>(u, Wa + (size_t)l * H_ * H_, ba + l * H_, h, stA, N_);
        bn_relu<<<ewGrid, 256, 0, stream>>>(h, stA, ga + l * H_, bea + l * H_, n4);
        gemm_stats<<<gemmGrid, 256, 0, stream>>>(h, Wb + (size_t)l * H_ * H_, bb + l * H_, u, stB, N_);
        bn_relu<<<ewGrid, 256, 0, stream>>>(u, stB, gb + l * H_, beb + l * H_, n4);
        // pool + output linear
        pool_sum<<<512, 128, 0, stream>>>(u, batch, pooled + (size_t)l * G_ * H_, N_);
        out_accum<<<G_, 64, 0, stream>>>(pooled + (size_t)l * G_ * H_, cntf,
                                         Wl + (size_t)l * H_ * T_, bl + l * T_, outacc);
        float* tmp = h; h = u; u = tmp;
    }

    sigmoid_k<<<(G_ * T_ + 255) / 256, 256, 0, stream>>>(outacc, out, G_ * T_);
}

// Round 3
// 1269.083 us; speedup vs baseline: 26.0092x; 1.3406x over previous
//
#include <hip/hip_runtime.h>
#include <hip/hip_bf16.h>

#define N_  100000
#define E_  1600000
#define G_  512
#define H_  128
#define T_  10
#define BN_EPS 1e-5f

typedef __attribute__((ext_vector_type(8))) short short8;
typedef __attribute__((ext_vector_type(4))) float floatx4;

__device__ __forceinline__ float bf2f(short s) {
    return __uint_as_float(((unsigned int)(unsigned short)s) << 16);
}
__device__ __forceinline__ short f2bf(float f) {
    unsigned int u = __float_as_uint(f);
    u += 0x7fffu + ((u >> 16) & 1u);          // round-to-nearest-even
    return (short)(u >> 16);
}

// ---------------------------------------------------------------------------
// MFMA GEMM: C[nrows x 128](bf16) = act(A) @ W + bias, fused BN-stats output.
// mode 0: A bf16, plain.  mode 1: A bf16, apply BN(scale/shift from statsIn)
// + ReLU during A-load.  mode 2: A fp32, plain (layer-0 x input).
// Block = 256 thr (4 waves), tile 64 rows x 128 cols. W^T (n-major) in LDS.
// ---------------------------------------------------------------------------
__global__ __launch_bounds__(256) void gemm_mfma(
    const void* __restrict__ Ain, const short* __restrict__ Wt,
    const float* __restrict__ bias, short* __restrict__ Cout,
    float* __restrict__ statsOut,
    const float* __restrict__ statsIn, const float* __restrict__ gamma,
    const float* __restrict__ beta, int mode, int nrows)
{
    __shared__ __align__(16) short Bs[128][136];   // W^T, padded (2-way LDS alias = free)
    __shared__ float scale_s[128];
    __shared__ float shift_s[128];

    const int tid = threadIdx.x;

    // Stage W^T (row n = output col, 128 bf16 of k) into LDS
    {
        int r = tid >> 1;
        int half = (tid & 1) << 6;
        const short* g = Wt + r * 128 + half;
        short* d = &Bs[r][half];
#pragma unroll
        for (int i = 0; i < 8; ++i)
            *(short8*)(d + i * 8) = *(const short8*)(g + i * 8);
    }
    if (mode == 1 && tid < 128) {
        const float nInv = 1.0f / (float)N_;
        float mu = statsIn[tid] * nInv;
        float var = statsIn[128 + tid] * nInv - mu * mu;
        float sc = gamma[tid] * rsqrtf(var + BN_EPS);
        scale_s[tid] = sc;
        shift_s[tid] = beta[tid] - mu * sc;
    }
    __syncthreads();

    const int wave = tid >> 6;
    const int lane = tid & 63;
    const int m = lane & 15;
    const int quad = lane >> 4;
    const int rowBase = blockIdx.x * 64;
    int row = rowBase + wave * 16 + m;
    int arow = row < nrows ? row : nrows - 1;   // clamp; garbage rows masked later

    floatx4 acc[8];
#pragma unroll
    for (int i = 0; i < 8; ++i) acc[i] = (floatx4)0.f;

#pragma unroll
    for (int k0 = 0; k0 < 128; k0 += 32) {
        const int kb = k0 + quad * 8;
        short8 af;
        if (mode == 2) {
            const float* Af = (const float*)Ain + (size_t)arow * 128 + kb;
            float4 x0 = *(const float4*)(Af);
            float4 x1 = *(const float4*)(Af + 4);
            af[0] = f2bf(x0.x); af[1] = f2bf(x0.y); af[2] = f2bf(x0.z); af[3] = f2bf(x0.w);
            af[4] = f2bf(x1.x); af[5] = f2bf(x1.y); af[6] = f2bf(x1.z); af[7] = f2bf(x1.w);
        } else {
            af = *(const short8*)((const short*)Ain + (size_t)arow * 128 + kb);
            if (mode == 1) {
                float4 sc0 = *(const float4*)&scale_s[kb];
                float4 sc1 = *(const float4*)&scale_s[kb + 4];
                float4 sh0 = *(const float4*)&shift_s[kb];
                float4 sh1 = *(const float4*)&shift_s[kb + 4];
                af[0] = f2bf(fmaxf(fmaf(bf2f(af[0]), sc0.x, sh0.x), 0.f));
                af[1] = f2bf(fmaxf(fmaf(bf2f(af[1]), sc0.y, sh0.y), 0.f));
                af[2] = f2bf(fmaxf(fmaf(bf2f(af[2]), sc0.z, sh0.z), 0.f));
                af[3] = f2bf(fmaxf(fmaf(bf2f(af[3]), sc0.w, sh0.w), 0.f));
                af[4] = f2bf(fmaxf(fmaf(bf2f(af[4]), sc1.x, sh1.x), 0.f));
                af[5] = f2bf(fmaxf(fmaf(bf2f(af[5]), sc1.y, sh1.y), 0.f));
                af[6] = f2bf(fmaxf(fmaf(bf2f(af[6]), sc1.z, sh1.z), 0.f));
                af[7] = f2bf(fmaxf(fmaf(bf2f(af[7]), sc1.w, sh1.w), 0.f));
            }
        }
#pragma unroll
        for (int nt = 0; nt < 8; ++nt) {
            short8 bf = *(const short8*)&Bs[nt * 16 + m][kb];
            acc[nt] = __builtin_amdgcn_mfma_f32_16x16x32_bf16(af, bf, acc[nt], 0, 0, 0);
        }
    }

    // Epilogue: bias add into LDS (reuse Bs as fp32 C tile), then coalesced
    // bf16 store + per-column BN stats.
    __syncthreads();
    float (*Cs)[132] = (float(*)[132])&Bs[0][0];   // 64*132*4 = 33792 B <= sizeof(Bs)
#pragma unroll
    for (int nt = 0; nt < 8; ++nt) {
        float b = bias[nt * 16 + m];
#pragma unroll
        for (int r = 0; r < 4; ++r)
            Cs[wave * 16 + quad * 4 + r][nt * 16 + m] = acc[nt][r] + b;
    }
    __syncthreads();

    {
        int trow = tid >> 2;
        int tcg = (tid & 3) << 5;
        int grow = rowBase + trow;
        if (grow < nrows) {
            short* dst = Cout + (size_t)grow * 128 + tcg;
#pragma unroll
            for (int i = 0; i < 4; ++i) {
                short8 o;
#pragma unroll
                for (int j = 0; j < 8; ++j) o[j] = f2bf(Cs[trow][tcg + i * 8 + j]);
                *(short8*)(dst + i * 8) = o;
            }
        }
    }
    if (tid < 128) {
        int nvalid = nrows - rowBase;
        if (nvalid > 64) nvalid = 64;
        float S1 = 0.f, S2 = 0.f;
        for (int r = 0; r < nvalid; ++r) {
            float v = Cs[r][tid];
            S1 += v; S2 += v * v;
        }
        atomicAdd(&statsOut[tid], S1);
        atomicAdd(&statsOut[128 + tid], S2);
    }
}

// ---------------------------------------------------------------------------
// BN apply + ReLU + segment pool, streaming. Block=128 thr (thread = column).
// ---------------------------------------------------------------------------
__global__ __launch_bounds__(128) void bn_relu_pool(
    const short* __restrict__ Cin, short* __restrict__ hout,
    const float* __restrict__ stats, const float* __restrict__ gamma,
    const float* __restrict__ beta, const int* __restrict__ batch,
    float* __restrict__ pooled, int n)
{
    int c = threadIdx.x;
    const float nInv = 1.0f / (float)N_;
    float mu = stats[c] * nInv;
    float var = stats[128 + c] * nInv - mu * mu;
    float sc = gamma[c] * rsqrtf(var + BN_EPS);
    float sh = beta[c] - mu * sc;

    int per = (n + gridDim.x - 1) / gridDim.x;
    int r0 = blockIdx.x * per;
    int r1 = min(n, r0 + per);
    if (r0 >= r1) return;
    int curg = batch[r0];
    float s = 0.f;
    for (int r = r0; r < r1; ++r) {
        int g = batch[r];
        if (g != curg) {
            atomicAdd(&pooled[(size_t)curg * 128 + c], s);
            s = 0.f;
            curg = g;
        }
        float v = fmaxf(fmaf(bf2f(Cin[(size_t)r * 128 + c]), sc, sh), 0.f);
        hout[(size_t)r * 128 + c] = f2bf(v);
        s += v;
    }
    atomicAdd(&pooled[(size_t)curg * 128 + c], s);
}

// ---------------------------------------------------------------------------
// CSR build
// ---------------------------------------------------------------------------
__global__ void hist_dst(const int* __restrict__ dst, int* __restrict__ cnt, int e)
{
    int i = blockIdx.x * blockDim.x + threadIdx.x;
    if (i < e) atomicAdd(&cnt[dst[i]], 1);
}

__global__ __launch_bounds__(256) void scan1(const int* __restrict__ cnt,
                                             int* __restrict__ off,
                                             int* __restrict__ bsum, int n)
{
    __shared__ int sd[256];
    int t = threadIdx.x;
    int base = blockIdx.x * 1024 + t * 4;
    int c0 = (base + 0 < n) ? cnt[base + 0] : 0;
    int c1 = (base + 1 < n) ? cnt[base + 1] : 0;
    int c2 = (base + 2 < n) ? cnt[base + 2] : 0;
    int c3 = (base + 3 < n) ? cnt[base + 3] : 0;
    int s = c0 + c1 + c2 + c3;
    sd[t] = s;
    __syncthreads();
    for (int d = 1; d < 256; d <<= 1) {
        int v = (t >= d) ? sd[t - d] : 0;
        __syncthreads();
        sd[t] += v;
        __syncthreads();
    }
    int p = sd[t] - s;
    if (base + 0 < n) off[base + 0] = p;
    if (base + 1 < n) off[base + 1] = p + c0;
    if (base + 2 < n) off[base + 2] = p + c0 + c1;
    if (base + 3 < n) off[base + 3] = p + c0 + c1 + c2;
    if (t == 255) bsum[blockIdx.x] = sd[255];
}

__global__ __launch_bounds__(128) void scan2(int* __restrict__ bsum, int nb)
{
    __shared__ int sd[128];
    int t = threadIdx.x;
    int v0 = (t < nb) ? bsum[t] : 0;
    sd[t] = v0;
    __syncthreads();
    for (int d = 1; d < 128; d <<= 1) {
        int v = (t >= d) ? sd[t - d] : 0;
        __syncthreads();
        sd[t] += v;
        __syncthreads();
    }
    if (t < nb) bsum[t] = sd[t] - v0;
}

__global__ __launch_bounds__(256) void scan3(int* __restrict__ off,
                                             int* __restrict__ cur,
                                             const int* __restrict__ bsum, int n)
{
    int t = threadIdx.x;
    int base = blockIdx.x * 1024 + t * 4;
    int add = bsum[blockIdx.x];
#pragma unroll
    for (int i = 0; i < 4; ++i) {
        if (base + i < n) {
            int v = off[base + i] + add;
            off[base + i] = v;
            cur[base + i] = v;
        }
    }
    if (blockIdx.x == 0 && t == 0) off[n] = E_;
}

__global__ void fill_csr(const int* __restrict__ src, const int* __restrict__ dst,
                         int* __restrict__ cur, int* __restrict__ eidx, int e)
{
    int i = blockIdx.x * blockDim.x + threadIdx.x;
    if (i >= e) return;
    int d = dst[i];
    int pos = atomicAdd(&cur[d], 1);
    eidx[pos] = src[i];
}

// ---------------------------------------------------------------------------
// GIN aggregation (bf16): u[i] = (1+eps)*h[i] + sum_{j in N(i)} h[j]
// One wave per node; lane = 2 columns (4 B) -> 256 B coalesced per neighbor.
// ---------------------------------------------------------------------------
__global__ __launch_bounds__(256) void aggregate(
    const short* __restrict__ h, short* __restrict__ u,
    const int* __restrict__ off, const int* __restrict__ eidx,
    const float* __restrict__ eps, int li)
{
    int node = blockIdx.x * 4 + (threadIdx.x >> 6);
    if (node >= N_) return;
    int lane = threadIdx.x & 63;
    int col = lane * 2;

    int s0 = off[node];
    int s1 = off[node + 1];
    float se = 1.0f + eps[li];

    ushort2 a = *(const ushort2*)(h + (size_t)node * 128 + col);
    float ax = bf2f((short)a.x) * se;
    float ay = bf2f((short)a.y) * se;

    int j = s0;
    for (; j + 1 < s1; j += 2) {
        int na = eidx[j];
        int nb = eidx[j + 1];
        ushort2 va = *(const ushort2*)(h + (size_t)na * 128 + col);
        ushort2 vb = *(const ushort2*)(h + (size_t)nb * 128 + col);
        ax += bf2f((short)va.x) + bf2f((short)vb.x);
        ay += bf2f((short)va.y) + bf2f((short)vb.y);
    }
    if (j < s1) {
        int na = eidx[j];
        ushort2 va = *(const ushort2*)(h + (size_t)na * 128 + col);
        ax += bf2f((short)va.x);
        ay += bf2f((short)va.y);
    }
    ushort2 o;
    o.x = (unsigned short)f2bf(ax);
    o.y = (unsigned short)f2bf(ay);
    *(ushort2*)(u + (size_t)node * 128 + col) = o;
}

// ---------------------------------------------------------------------------
__global__ void count_nodes(const int* __restrict__ batch, float* __restrict__ cnt, int n)
{
    int i = blockIdx.x * blockDim.x + threadIdx.x;
    if (i < n) atomicAdd(&cnt[batch[i]], 1.0f);
}

__global__ void out_accum(const float* __restrict__ pooled, const float* __restrict__ cnt,
                          const float* __restrict__ Wl, const float* __restrict__ bl,
                          float* __restrict__ outacc)
{
    int g = blockIdx.x;
    int t = threadIdx.x;
    if (t >= T_) return;
    float inv = 1.0f / fmaxf(cnt[g], 1.0f);
    float acc = 0.f;
    for (int c = 0; c < 128; ++c)
        acc = fmaf(pooled[(size_t)g * 128 + c], Wl[c * T_ + t], acc);
    outacc[g * T_ + t] += acc * inv + bl[t];
}

__global__ void sigmoid_k(const float* __restrict__ in, float* __restrict__ out, int n)
{
    int i = blockIdx.x * blockDim.x + threadIdx.x;
    if (i < n) out[i] = 1.0f / (1.0f + expf(-in[i]));
}

// Transpose + convert Wa/Wb -> bf16 W^T[mat][n*128+k]; mats 0..3 = Wa, 4..7 = Wb
__global__ void convert_W(const float* __restrict__ Wa, const float* __restrict__ Wb,
                          short* __restrict__ Wt)
{
    int t = blockIdx.x * blockDim.x + threadIdx.x;
    if (t >= 8 * 16384) return;
    int mat = t >> 14;
    int rem = t & 16383;
    int k = rem >> 7;
    int n = rem & 127;
    const float* W = (mat < 4) ? (Wa + (size_t)mat * 16384) : (Wb + (size_t)(mat - 4) * 16384);
    float v = W[k * 128 + n];                    // coalesced read
    Wt[(size_t)mat * 16384 + n * 128 + k] = f2bf(v);
}

// ---------------------------------------------------------------------------
extern "C" void kernel_launch(void* const* d_in, const int* in_sizes, int n_in,
                              void* d_out, int out_size, void* d_ws, size_t ws_size,
                              hipStream_t stream)
{
    const float* x    = (const float*)d_in[0];
    const int*   ei   = (const int*)d_in[1];
    const int*   batch= (const int*)d_in[2];
    const float* Wa   = (const float*)d_in[3];
    const float* ba   = (const float*)d_in[4];
    const float* ga   = (const float*)d_in[5];
    const float* bea  = (const float*)d_in[6];
    const float* Wb   = (const float*)d_in[7];
    const float* bb   = (const float*)d_in[8];
    const float* gb   = (const float*)d_in[9];
    const float* beb  = (const float*)d_in[10];
    const float* Wl   = (const float*)d_in[11];
    const float* bl   = (const float*)d_in[12];
    const float* eps  = (const float*)d_in[13];
    float* out = (float*)d_out;

    const size_t NH = (size_t)N_ * H_;
    short* Cb = (short*)d_ws;        // gemm-A raw output (pre-BN), bf16
    short* Db = Cb + NH;             // gemm-B raw output (pre-BN), bf16
    short* hb = Db + NH;             // post-BN activation, bf16
    short* ub = hb + NH;             // aggregated input, bf16
    short* Wt = ub + NH;             // 8 x 128 x 128 bf16 (transposed weights)
    float* stats  = (float*)(Wt + 8 * 16384);   // 8 x 256
    float* pooled = stats + 8 * 256;            // 4 x G x 128
    float* cntf   = pooled + 4 * (size_t)G_ * H_;
    float* outacc = cntf + G_;
    int*   cur    = (int*)(outacc + (size_t)G_ * T_);
    int*   off    = cur + N_;
    int*   eidx   = off + (N_ + 1);
    int*   bsum   = eidx + E_;       // 128 ints

    size_t zbytes = (size_t)(8 * 256 + 4 * G_ * H_ + G_ + G_ * T_ + N_) * sizeof(float);
    hipMemsetAsync(stats, 0, zbytes, stream);

    const int* esrc = ei;
    const int* edst = ei + E_;

    convert_W<<<(8 * 16384 + 255) / 256, 256, 0, stream>>>(Wa, Wb, Wt);

    // CSR build
    hist_dst<<<(E_ + 255) / 256, 256, 0, stream>>>(edst, cur, E_);
    const int nScanBlocks = (N_ + 1023) / 1024;
    scan1<<<nScanBlocks, 256, 0, stream>>>(cur, off, bsum, N_);
    scan2<<<1, 128, 0, stream>>>(bsum, nScanBlocks);
    scan3<<<nScanBlocks, 256, 0, stream>>>(off, cur, bsum, N_);
    fill_csr<<<(E_ + 255) / 256, 256, 0, stream>>>(esrc, edst, cur, eidx, E_);

    count_nodes<<<(N_ + 255) / 256, 256, 0, stream>>>(batch, cntf, N_);

    const int gemmGrid = (N_ + 63) / 64;
    const int aggGrid = (N_ + 3) / 4;

    // ---- layer 0 ----
    gemm_mfma<<<gemmGrid, 256, 0, stream>>>(x, Wt, ba, Cb, stats,
                                            nullptr, nullptr, nullptr, 2, N_);
    gemm_mfma<<<gemmGrid, 256, 0, stream>>>(Cb, Wt + 4 * 16384, bb, Db, stats + 256,
                                            stats, ga, bea, 1, N_);
    bn_relu_pool<<<1024, 128, 0, stream>>>(Db, hb, stats + 256, gb, beb, batch, pooled, N_);
    out_accum<<<G_, 64, 0, stream>>>(pooled, cntf, Wl, bl, outacc);

    for (int l = 1; l < 4; ++l) {
        float* stA = stats + (size_t)(2 * l) * 256;
        float* stB = stats + (size_t)(2 * l + 1) * 256;
        aggregate<<<aggGrid, 256, 0, stream>>>(hb, ub, off, eidx, eps, l - 1);
        gemm_mfma<<<gemmGrid, 256, 0, stream>>>(ub, Wt + (size_t)l * 16384,
                                                ba + l * H_, Cb, stA,
                                                nullptr, nullptr, nullptr, 0, N_);
        gemm_mfma<<<gemmGrid, 256, 0, stream>>>(Cb, Wt + (size_t)(4 + l) * 16384,
                                                bb + l * H_, Db, stB,
                                                stA, ga + l * H_, bea + l * H_, 1, N_);
        bn_relu_pool<<<1024, 128, 0, stream>>>(Db, hb, stB, gb + l * H_, beb + l * H_,
                                               batch, pooled + (size_t)l * G_ * H_, N_);
        out_accum<<<G_, 64, 0, stream>>>(pooled + (size_t)l * G_ * H_, cntf,
                                         Wl + (size_t)l * H_ * T_, bl + l * T_, outacc);
    }

    sigmoid_k<<<(G_ * T_ + 255) / 256, 256, 0, stream>>>(outacc, out, G_ * T_);
}